// Round 7
// baseline (308.347 us; speedup 1.0000x reference)
//
#include <hip/hip_runtime.h>

#define NN 50000
#define HID 128
#define NE 800000
#define ET (NE + NN)          // edges + self loops
#define NEG_SLOPE 0.2f
#define CAP 64                // padded CSR slots per node (max deg ~45)
#define WTOT (3 * HID * HID)  // 49152
#define VTOT (3 * 3 * HID)    // 1152

typedef __attribute__((ext_vector_type(8))) short short8v;  // 8 bf16 = 4 VGPRs
typedef __attribute__((ext_vector_type(4))) float f32x4;    // MFMA accumulator

__device__ inline float b2f(unsigned short u) {
    union { unsigned int i; float f; } x; x.i = ((unsigned int)u) << 16; return x.f;
}
__device__ inline unsigned short f2b(float f) {
    unsigned int x; __builtin_memcpy(&x, &f, 4);
    unsigned int lsb = (x >> 16) & 1u;
    x += 0x7fffu + lsb;                  // round-to-nearest-even
    return (unsigned short)(x >> 16);
}
// split fp32 into bf16 hi + bf16 lo so that b2f(hi)+b2f(lo) ~= v (rel err ~2^-17)
__device__ inline void splitbf(float v, unsigned short& hi, unsigned short& lo) {
    hi = f2b(v);
    lo = f2b(v - b2f(hi));
}

// ---------- fused prep: dtype flag + W split + param vectors + pos zero ----------
__global__ __launch_bounds__(256) void prep(
        const unsigned short* __restrict__ z, const void* __restrict__ Ws,
        const void* __restrict__ as_, const void* __restrict__ ad_,
        const void* __restrict__ b_, unsigned short* __restrict__ Wb,
        float* __restrict__ asf, float* __restrict__ adf, float* __restrict__ bff,
        int* __restrict__ pos, int* __restrict__ flag) {
    __shared__ int sflag;
    const int t = threadIdx.x;
    if (t < 64) {   // wave 0: bf16-vs-fp32 probe (128 even-halfword samples of z)
        unsigned short a = z[t * 4];
        unsigned short b = z[t * 4 + 2];
        int ea = (a >> 7) & 0xFF, eb = (b >> 7) & 0xFF;
        int w1 = (ea >= 0x9A || (ea <= 0x30 && a != 0)) ? 1 : 0;
        int w2 = (eb >= 0x9A || (eb <= 0x30 && b != 0)) ? 1 : 0;
        int wild = __popcll(__ballot(w1)) + __popcll(__ballot(w2));
        if (t == 0) sflag = (wild < 8) ? 1 : 0;
    }
    __syncthreads();
    const int f = sflag;
    const int gtid = blockIdx.x * 256 + t;
    if (gtid == 0) *flag = f;
    if (gtid < NN) pos[gtid] = 0;            // degree array zero (replaces memset)
    if (gtid < WTOT) {
        // W -> [hi: W^T k-contig][lo: W^T k-contig] (plain; gemm reads L1/L2-hot)
        int L = gtid >> 14, k = (gtid >> 7) & 127, n = gtid & 127;
        float v = f ? b2f(((const unsigned short*)Ws)[gtid]) : ((const float*)Ws)[gtid];
        unsigned short hi, lo;
        splitbf(v, hi, lo);
        unsigned short* hbase = Wb + (size_t)L * 2 * HID * HID;
        unsigned short* lbase = hbase + HID * HID;
        hbase[n * HID + k] = hi;
        lbase[n * HID + k] = lo;
    } else {
        int i = gtid - WTOT;
        if (i < VTOT) {                      // a_s, a_d, bias -> fp32
            int which = i / (3 * HID), j = i - which * (3 * HID);
            const void* in = which == 0 ? as_ : which == 1 ? ad_ : b_;
            float* o = which == 0 ? asf : which == 1 ? adf : bff;
            o[j] = f ? b2f(((const unsigned short*)in)[j]) : ((const float*)in)[j];
        }
    }
}

// ---------- padded-CSR scatter, XCD-swizzled ----------
#define SCHUNK 1024
__global__ __launch_bounds__(256) void scatter_padded(
        const int* __restrict__ ei, int* __restrict__ pos, int* __restrict__ csr) {
    const int rng  = blockIdx.x & 7;
    const int base = (blockIdx.x >> 3) * SCHUNK;
#pragma unroll
    for (int k = 0; k < SCHUNK / 256; ++k) {
        int e = base + k * 256 + threadIdx.x;
        if (e >= ET) continue;
        int d = (e < NE) ? ei[NE + e] : (e - NE);
        if ((d * 8) / NN != rng) continue;        // not my dst range
        int s = (e < NE) ? ei[e] : d;
        int slot = atomicAdd(&pos[d], 1);
        if (slot < CAP) csr[(d << 6) + slot] = s;
    }
}

// ---------- MFMA GEMM v3 (x = h@W) + per-node attention logits ----------
// 64 rows/block, 2x2 wave split: wave (wr,wc) owns rows [wr*32,+32) x cols
// [wc*64,+64). Same MFMA/output as before, but per-wave B-fragment traffic
// HALVES (32 KB vs 64 KB) and there is NO LDS staging / big barrier: W is
// 64 KB shared by all 782 blocks -> L1/L2-resident by nature, so bhi/blo load
// straight from global. Only LDS: 512 B for the cross-wc alpha combine.
// Accumulation order per output identical to v2 (ks-ordered, hihi/lohi/hilo).
// C/D layout (HW-verified): col = lane&15, row = (lane>>4)*4 + reg.
__global__ __launch_bounds__(256) void gemm_alpha(
        const void* __restrict__ h_, const unsigned short* __restrict__ Wb,
        const float* __restrict__ a_s, const float* __restrict__ a_d,
        unsigned short* __restrict__ x, float* __restrict__ alpha_s, float* __restrict__ alpha_d,
        const int* __restrict__ flag) {
    __shared__ float aps[64], apd[64];      // wc=1 alpha partials, per block row
    const int t = threadIdx.x;
    const int base = blockIdx.x * 64;
    const int hf = *flag;
    const unsigned short* Whi = Wb;
    const unsigned short* Wlo = Wb + HID * HID;

    const int w  = t >> 6;
    const int l  = t & 63;
    const int wr = w >> 1;    // row half
    const int wc = w & 1;     // col half
    const int lr = l & 15;    // A row / B,D col within 16
    const int lk = l >> 4;    // quarter: k sub-block

    // ---- A fragments: 2 row-stripes x 4 k-slices, straight from global ----
    const short8v zv = (short8v){0, 0, 0, 0, 0, 0, 0, 0};
    short8v ahi[2][4], alo[2][4];
#pragma unroll
    for (int ms = 0; ms < 2; ++ms) {
        const int arow = base + wr * 32 + ms * 16 + lr;
        const bool rowok = (arow < NN);
        if (hf) {
            const unsigned short* hp = (const unsigned short*)h_ + (size_t)arow * HID + lk * 8;
#pragma unroll
            for (int ks = 0; ks < 4; ++ks) {
                ahi[ms][ks] = rowok ? *(const short8v*)(hp + ks * 32) : zv;
                alo[ms][ks] = zv;
            }
        } else {
            const float* hp = (const float*)h_ + (size_t)arow * HID + lk * 8;
#pragma unroll
            for (int ks = 0; ks < 4; ++ks) {
                float4 v0 = make_float4(0.f, 0.f, 0.f, 0.f), v1 = v0;
                if (rowok) {
                    v0 = *(const float4*)(hp + ks * 32);
                    v1 = *(const float4*)(hp + ks * 32 + 4);
                }
                ushort4 h0, l0, h1, l1;
                splitbf(v0.x, h0.x, l0.x); splitbf(v0.y, h0.y, l0.y);
                splitbf(v0.z, h0.z, l0.z); splitbf(v0.w, h0.w, l0.w);
                splitbf(v1.x, h1.x, l1.x); splitbf(v1.y, h1.y, l1.y);
                splitbf(v1.z, h1.z, l1.z); splitbf(v1.w, h1.w, l1.w);
                ahi[ms][ks] = (short8v){(short)h0.x, (short)h0.y, (short)h0.z, (short)h0.w,
                                        (short)h1.x, (short)h1.y, (short)h1.z, (short)h1.w};
                alo[ms][ks] = (short8v){(short)l0.x, (short)l0.y, (short)l0.z, (short)l0.w,
                                        (short)l1.x, (short)l1.y, (short)l1.z, (short)l1.w};
            }
        }
    }

    // ---- MFMA main: 4 ks x 4 nt x 2 ms ----
    f32x4 acc[2][4];
#pragma unroll
    for (int ms = 0; ms < 2; ++ms)
#pragma unroll
        for (int nt = 0; nt < 4; ++nt) acc[ms][nt] = (f32x4){0.f, 0.f, 0.f, 0.f};

    if (hf) {
#pragma unroll
        for (int ks = 0; ks < 4; ++ks) {
#pragma unroll
            for (int nt = 0; nt < 4; ++nt) {
                int brow = wc * 64 + nt * 16 + lr;
                short8v bhi = *(const short8v*)(Whi + brow * HID + ks * 32 + lk * 8);
                short8v blo = *(const short8v*)(Wlo + brow * HID + ks * 32 + lk * 8);
#pragma unroll
                for (int ms = 0; ms < 2; ++ms) {
                    acc[ms][nt] = __builtin_amdgcn_mfma_f32_16x16x32_bf16(ahi[ms][ks], bhi, acc[ms][nt], 0, 0, 0);
                    acc[ms][nt] = __builtin_amdgcn_mfma_f32_16x16x32_bf16(ahi[ms][ks], blo, acc[ms][nt], 0, 0, 0);
                }
            }
        }
    } else {
#pragma unroll
        for (int ks = 0; ks < 4; ++ks) {
#pragma unroll
            for (int nt = 0; nt < 4; ++nt) {
                int brow = wc * 64 + nt * 16 + lr;
                short8v bhi = *(const short8v*)(Whi + brow * HID + ks * 32 + lk * 8);
                short8v blo = *(const short8v*)(Wlo + brow * HID + ks * 32 + lk * 8);
#pragma unroll
                for (int ms = 0; ms < 2; ++ms) {
                    acc[ms][nt] = __builtin_amdgcn_mfma_f32_16x16x32_bf16(ahi[ms][ks], bhi, acc[ms][nt], 0, 0, 0);
                    acc[ms][nt] = __builtin_amdgcn_mfma_f32_16x16x32_bf16(alo[ms][ks], bhi, acc[ms][nt], 0, 0, 0);
                    acc[ms][nt] = __builtin_amdgcn_mfma_f32_16x16x32_bf16(ahi[ms][ks], blo, acc[ms][nt], 0, 0, 0);
                }
            }
        }
    }

    // ---- epilogue: alpha partials (this wave's 64 cols), 16-lane reduce ----
    float ps[2][4] = {{0.f,0.f,0.f,0.f},{0.f,0.f,0.f,0.f}};
    float pd[2][4] = {{0.f,0.f,0.f,0.f},{0.f,0.f,0.f,0.f}};
#pragma unroll
    for (int nt = 0; nt < 4; ++nt) {
        float asv = a_s[wc * 64 + nt * 16 + lr];
        float adv = a_d[wc * 64 + nt * 16 + lr];
#pragma unroll
        for (int ms = 0; ms < 2; ++ms)
#pragma unroll
            for (int r = 0; r < 4; ++r) {
                ps[ms][r] = fmaf(acc[ms][nt][r], asv, ps[ms][r]);
                pd[ms][r] = fmaf(acc[ms][nt][r], adv, pd[ms][r]);
            }
    }
#pragma unroll
    for (int m = 8; m >= 1; m >>= 1)
#pragma unroll
        for (int ms = 0; ms < 2; ++ms)
#pragma unroll
            for (int r = 0; r < 4; ++r) {
                ps[ms][r] += __shfl_xor(ps[ms][r], m, 16);
                pd[ms][r] += __shfl_xor(pd[ms][r], m, 16);
            }
    // wc=1 publishes partials; wc=0 combines and stores
    if (wc == 1 && lr == 0) {
#pragma unroll
        for (int ms = 0; ms < 2; ++ms)
#pragma unroll
            for (int r = 0; r < 4; ++r) {
                int rib = wr * 32 + ms * 16 + lk * 4 + r;
                aps[rib] = ps[ms][r];
                apd[rib] = pd[ms][r];
            }
    }
    __syncthreads();

    // ---- stores: bf16 x (row-major) + alpha ----
#pragma unroll
    for (int ms = 0; ms < 2; ++ms)
#pragma unroll
        for (int r = 0; r < 4; ++r) {
            int rib = wr * 32 + ms * 16 + lk * 4 + r;
            int grow = base + rib;
            if (grow < NN) {
#pragma unroll
                for (int nt = 0; nt < 4; ++nt)
                    x[(size_t)grow * HID + wc * 64 + nt * 16 + lr] = f2b(acc[ms][nt][r]);
                if (wc == 0 && lr == 0) {
                    alpha_s[grow] = ps[ms][r] + aps[rib];
                    alpha_d[grow] = pd[ms][r] + apd[rib];
                }
            }
        }
}

// ---------- fused softmax + aggregation v3: register-resident edge state ----------
// Phase 1 (lane = CSR slot): one coalesced 256-B csr read, one als gather,
// ONE exp per edge, butterfly denominator, pre-normalized weight in a register.
// Phase 2 (lane = 2 feature cols): (idx_j, p_j) distributed by __shfl from
// registers -- no memory dependency between chunks, so gathers stream
// back-to-back (round-6 verified: removed the ~600 cyc/gather serial chain).
__global__ __launch_bounds__(256) void aggregate_v3(
        const unsigned short* __restrict__ x, const int* __restrict__ deg_,
        const int* __restrict__ csr, const float* __restrict__ als,
        const float* __restrict__ ald, const float* __restrict__ bias,
        void* __restrict__ out, const int* __restrict__ flag, int do_relu) {
    const int node = (blockIdx.x * 256 + threadIdx.x) >> 6;
    const int lane = threadIdx.x & 63;
    if (node >= NN) return;
    const int deg = min(deg_[node], CAP);

    // ---- phase 1: softmax weights, one lane per slot ----
    int   sidx = 0;
    float p    = 0.f;
    if (lane < deg) {
        sidx = csr[(node << 6) + lane];              // coalesced 256-B read
        float e = als[sidx] + ald[node];             // gather + broadcast
        e = fmaxf(e, NEG_SLOPE * e);                 // leaky_relu
        e = fminf(e, 60.f);                          // inf hardening
        p = __expf(e);
    }
    float den = p;
#pragma unroll
    for (int m = 1; m < 64; m <<= 1) den += __shfl_xor(den, m);
    p *= 1.f / (den + 1e-16f);                       // normalized; 0 on padding lanes

    // ---- phase 2: gather + weighted accumulate, lane = 2 cols ----
    const unsigned int* x2 = (const unsigned int*)x; // ushort2 as u32
    float ax = 0.f, ay = 0.f;
    for (int j0 = 0; j0 < deg; j0 += 16) {
        unsigned int u[16]; float pj[16];
#pragma unroll
        for (int k = 0; k < 16; ++k) {
            int j = j0 + k;                          // j <= 63 always (deg <= CAP = 64)
            int ij = __shfl(sidx, j);                // register broadcast, no mem dep
            pj[k] = __shfl(p, j);                    // 0 beyond deg
            u[k] = x2[((unsigned)ij << 6) + lane];   // 32-bit offset, 256-B row gather
        }
#pragma unroll
        for (int k = 0; k < 16; ++k) {
            ax = fmaf(pj[k], b2f((unsigned short)(u[k] & 0xFFFFu)), ax);
            ay = fmaf(pj[k], b2f((unsigned short)(u[k] >> 16)), ay);
        }
    }

    float2 bv = ((const float2*)bias)[lane];
    float ox = ax + bv.x;
    float oy = ay + bv.y;
    if (do_relu) { ox = fmaxf(ox, 0.f); oy = fmaxf(oy, 0.f); }
    if (*flag) {
        ushort2 pk; pk.x = f2b(ox); pk.y = f2b(oy);
        *(ushort2*)((unsigned short*)out + (size_t)node * HID + lane * 2) = pk;
    } else {
        ((float2*)out)[(size_t)node * 64 + lane] = make_float2(ox, oy);
    }
}

extern "C" void kernel_launch(void* const* d_in, const int* in_sizes, int n_in,
                              void* d_out, int out_size, void* d_ws, size_t ws_size,
                              hipStream_t stream) {
    const void* z_in  = d_in[0];
    const int*  ei    = (const int*)d_in[1];
    const void* Ws_in = d_in[2];
    const void* as_in = d_in[3];
    const void* ad_in = d_in[4];
    const void* b_in  = d_in[5];

    char* wsp = (char*)d_ws;
    auto alloc = [&](size_t bytes) -> char* {
        char* p = wsp; wsp += (bytes + 255) & ~(size_t)255; return p;
    };
    int*            dflag   = (int*)alloc(4);
    int*            pos     = (int*)alloc(NN * 4);               // degree array
    int*            csrp    = (int*)alloc((size_t)NN * CAP * 4); // padded CSR (12.8 MB)
    float*          alpha_s = (float*)alloc(NN * 4);
    float*          alpha_d = (float*)alloc(NN * 4);
    unsigned short* Wb      = (unsigned short*)alloc((size_t)3 * 2 * HID * HID * 2); // hi+lo W^T
    float*          asf     = (float*)alloc(3 * HID * 4);
    float*          adf     = (float*)alloc(3 * HID * 4);
    float*          bff     = (float*)alloc(3 * HID * 4);
    unsigned short* xb      = (unsigned short*)alloc((size_t)NN * HID * 2);  // row-major bf16 x

    // fused prep: flag + W split + vectors + pos zero
    prep<<<197, 256, 0, stream>>>((const unsigned short*)z_in, Ws_in, as_in, ad_in, b_in,
                                  Wb, asf, adf, bff, pos, dflag);

    // padded CSR build: single swizzled scatter pass
    const int chunks = (ET + SCHUNK - 1) / SCHUNK;
    scatter_padded<<<chunks * 8, 256, 0, stream>>>(ei, pos, csrp);

    const int gemm_blocks = (NN + 63) / 64;
    const int wave_blocks = (NN + 3) / 4;   // 4 waves (nodes) per 256-thread block
    const size_t WL = 2 * HID * HID;        // per-layer Wb stride (ushorts)

    // layer 0
    gemm_alpha<<<gemm_blocks, 256, 0, stream>>>(z_in, Wb, asf, adf, xb, alpha_s, alpha_d, dflag);
    aggregate_v3<<<wave_blocks, 256, 0, stream>>>(xb, pos, csrp, alpha_s, alpha_d, bff, d_out, dflag, 1);

    // layer 1 (d_out ping-pong: aggregate reads only xb/als/csr — overwrite safe)
    gemm_alpha<<<gemm_blocks, 256, 0, stream>>>(d_out, Wb + WL, asf + HID, adf + HID,
                                                xb, alpha_s, alpha_d, dflag);
    aggregate_v3<<<wave_blocks, 256, 0, stream>>>(xb, pos, csrp, alpha_s, alpha_d, bff + HID, d_out, dflag, 1);

    // layer 2 (final, no relu)
    gemm_alpha<<<gemm_blocks, 256, 0, stream>>>(d_out, Wb + 2 * WL, asf + 2 * HID,
                                                adf + 2 * HID, xb, alpha_s, alpha_d, dflag);
    aggregate_v3<<<wave_blocks, 256, 0, stream>>>(xb, pos, csrp, alpha_s, alpha_d, bff + 2 * HID, d_out, dflag, 0);
}

// Round 8
// 295.519 us; speedup vs baseline: 1.0434x; 1.0434x over previous
//
#include <hip/hip_runtime.h>

#define NN 50000
#define HID 128
#define NE 800000
#define ET (NE + NN)          // edges + self loops
#define NEG_SLOPE 0.2f
#define CAP 64                // padded CSR slots per node (max deg ~45)
#define WTOT (3 * HID * HID)  // 49152
#define VTOT (3 * 3 * HID)    // 1152

typedef __attribute__((ext_vector_type(8))) short short8v;  // 8 bf16 = 4 VGPRs
typedef __attribute__((ext_vector_type(4))) float f32x4;    // MFMA accumulator

__device__ inline float b2f(unsigned short u) {
    union { unsigned int i; float f; } x; x.i = ((unsigned int)u) << 16; return x.f;
}
__device__ inline float f_lo(unsigned int u) {       // low bf16 of packed pair
    union { unsigned int i; float f; } x; x.i = u << 16; return x.f;
}
__device__ inline float f_hi(unsigned int u) {       // high bf16 of packed pair
    union { unsigned int i; float f; } x; x.i = u & 0xFFFF0000u; return x.f;
}
__device__ inline unsigned short f2b(float f) {
    unsigned int x; __builtin_memcpy(&x, &f, 4);
    unsigned int lsb = (x >> 16) & 1u;
    x += 0x7fffu + lsb;                  // round-to-nearest-even
    return (unsigned short)(x >> 16);
}
// split fp32 into bf16 hi + bf16 lo so that b2f(hi)+b2f(lo) ~= v (rel err ~2^-17)
__device__ inline void splitbf(float v, unsigned short& hi, unsigned short& lo) {
    hi = f2b(v);
    lo = f2b(v - b2f(hi));
}
// readlane (SALU broadcast) of a float from a compile-time lane
__device__ inline float readlane_f(float v, int l) {
    union { float f; int i; } x; x.f = v;
    x.i = __builtin_amdgcn_readlane(x.i, l);
    return x.f;
}

// ---------- fused prep: dtype flag + W split/swizzle + param vectors + pos zero ----------
__global__ __launch_bounds__(256) void prep(
        const unsigned short* __restrict__ z, const void* __restrict__ Ws,
        const void* __restrict__ as_, const void* __restrict__ ad_,
        const void* __restrict__ b_, unsigned short* __restrict__ Wb,
        float* __restrict__ asf, float* __restrict__ adf, float* __restrict__ bff,
        int* __restrict__ pos, int* __restrict__ flag) {
    __shared__ int sflag;
    const int t = threadIdx.x;
    if (t < 64) {   // wave 0: bf16-vs-fp32 probe (128 even-halfword samples of z)
        unsigned short a = z[t * 4];
        unsigned short b = z[t * 4 + 2];
        int ea = (a >> 7) & 0xFF, eb = (b >> 7) & 0xFF;
        int w1 = (ea >= 0x9A || (ea <= 0x30 && a != 0)) ? 1 : 0;
        int w2 = (eb >= 0x9A || (eb <= 0x30 && b != 0)) ? 1 : 0;
        int wild = __popcll(__ballot(w1)) + __popcll(__ballot(w2));
        if (t == 0) sflag = (wild < 8) ? 1 : 0;
    }
    __syncthreads();
    const int f = sflag;
    const int gtid = blockIdx.x * 256 + t;
    if (gtid == 0) *flag = f;
    if (gtid < NN) pos[gtid] = 0;            // degree array zero (replaces memset)
    if (gtid < WTOT) {
        // W -> [hi: 32 KB XOR-swizzled LDS image, k-contig][lo: plain W^T, k-contig]
        int L = gtid >> 14, k = (gtid >> 7) & 127, n = gtid & 127;
        float v = f ? b2f(((const unsigned short*)Ws)[gtid]) : ((const float*)Ws)[gtid];
        unsigned short hi, lo;
        splitbf(v, hi, lo);
        unsigned short* hbase = Wb + (size_t)L * 2 * HID * HID;
        unsigned short* lbase = hbase + HID * HID;
        int bo = (n * 256 + k * 2) ^ ((n & 7) << 4);
        *(unsigned short*)((char*)hbase + bo) = hi;
        lbase[n * HID + k] = lo;
    } else {
        int i = gtid - WTOT;
        if (i < VTOT) {                      // a_s, a_d, bias -> fp32
            int which = i / (3 * HID), j = i - which * (3 * HID);
            const void* in = which == 0 ? as_ : which == 1 ? ad_ : b_;
            float* o = which == 0 ? asf : which == 1 ? adf : bff;
            o[j] = f ? b2f(((const unsigned short*)in)[j]) : ((const float*)in)[j];
        }
    }
}

// ---------- padded-CSR scatter, XCD-swizzled ----------
#define SCHUNK 1024
__global__ __launch_bounds__(256) void scatter_padded(
        const int* __restrict__ ei, int* __restrict__ pos, int* __restrict__ csr) {
    const int rng  = blockIdx.x & 7;
    const int base = (blockIdx.x >> 3) * SCHUNK;
#pragma unroll
    for (int k = 0; k < SCHUNK / 256; ++k) {
        int e = base + k * 256 + threadIdx.x;
        if (e >= ET) continue;
        int d = (e < NE) ? ei[NE + e] : (e - NE);
        if ((d * 8) / NN != rng) continue;        // not my dst range
        int s = (e < NE) ? ei[e] : d;
        int slot = atomicAdd(&pos[d], 1);
        if (slot < CAP) csr[(d << 6) + slot] = s;
    }
}

// ---------- MFMA GEMM v2 (x = h@W) + per-node attention logits ----------
// [round-6 best config, reverted from v3: the 2x2 no-LDS variant was +4 us/layer]
// A direct global->reg (waves own disjoint 16-row stripes); W-hi staged via
// linear 32-KB copy of prep's pre-swizzled image; W-lo from L2-hot global.
// C/D layout (HW-verified): col = lane&15, row = (lane>>4)*4 + reg.
__global__ __launch_bounds__(256) void gemm_alpha(
        const void* __restrict__ h_, const unsigned short* __restrict__ Wb,
        const float* __restrict__ a_s, const float* __restrict__ a_d,
        unsigned short* __restrict__ x, float* __restrict__ alpha_s, float* __restrict__ alpha_d,
        const int* __restrict__ flag) {
    __shared__ unsigned short Wh[HID * HID];   // 32 KB swizzled W-hi image
    const int t = threadIdx.x;
    const int base = blockIdx.x * 64;
    const int hf = *flag;
    const unsigned short* Wlo = Wb + HID * HID;

    // stage W-hi: linear 32-KB copy (swizzle already baked into Wb)
#pragma unroll
    for (int i = 0; i < 8; ++i) {
        int c = i * 256 + t;                  // 16-B chunk id, 2048 total
        ((short8v*)Wh)[c] = ((const short8v*)Wb)[c];
    }
    __syncthreads();

    const int w  = t >> 6;
    const int l  = t & 63;
    const int lr = l & 15;    // A row / B,D col within 16
    const int lk = l >> 4;    // quarter: k sub-block
    const int arow = base + w * 16 + lr;
    const bool rowok = (arow < NN);

    // ---- A fragments for all 4 k-slices, straight from global ----
    const short8v zv = (short8v){0, 0, 0, 0, 0, 0, 0, 0};
    short8v ahi[4], alo[4];
    if (hf) {
        const unsigned short* hp = (const unsigned short*)h_ + (size_t)arow * HID + lk * 8;
#pragma unroll
        for (int ks = 0; ks < 4; ++ks) {
            ahi[ks] = rowok ? *(const short8v*)(hp + ks * 32) : zv;
            alo[ks] = zv;
        }
    } else {
        const float* hp = (const float*)h_ + (size_t)arow * HID + lk * 8;
#pragma unroll
        for (int ks = 0; ks < 4; ++ks) {
            float4 v0 = make_float4(0.f, 0.f, 0.f, 0.f), v1 = v0;
            if (rowok) {
                v0 = *(const float4*)(hp + ks * 32);
                v1 = *(const float4*)(hp + ks * 32 + 4);
            }
            ushort4 h0, l0, h1, l1;
            splitbf(v0.x, h0.x, l0.x); splitbf(v0.y, h0.y, l0.y);
            splitbf(v0.z, h0.z, l0.z); splitbf(v0.w, h0.w, l0.w);
            splitbf(v1.x, h1.x, l1.x); splitbf(v1.y, h1.y, l1.y);
            splitbf(v1.z, h1.z, l1.z); splitbf(v1.w, h1.w, l1.w);
            ahi[ks] = (short8v){(short)h0.x, (short)h0.y, (short)h0.z, (short)h0.w,
                                (short)h1.x, (short)h1.y, (short)h1.z, (short)h1.w};
            alo[ks] = (short8v){(short)l0.x, (short)l0.y, (short)l0.z, (short)l0.w,
                                (short)l1.x, (short)l1.y, (short)l1.z, (short)l1.w};
        }
    }

    // ---- MFMA main ----
    f32x4 acc[8];
#pragma unroll
    for (int nt = 0; nt < 8; ++nt) acc[nt] = (f32x4){0.f, 0.f, 0.f, 0.f};

    if (hf) {
#pragma unroll
        for (int ks = 0; ks < 4; ++ks) {
#pragma unroll
            for (int nt = 0; nt < 8; ++nt) {
                int row = nt * 16 + lr;
                int bo = (row * 256 + ks * 64 + lk * 16) ^ ((lr & 7) << 4);
                short8v bhi = *(const short8v*)((const char*)Wh + bo);
                short8v blo = *(const short8v*)(Wlo + row * HID + ks * 32 + lk * 8);
                acc[nt] = __builtin_amdgcn_mfma_f32_16x16x32_bf16(ahi[ks], bhi, acc[nt], 0, 0, 0);
                acc[nt] = __builtin_amdgcn_mfma_f32_16x16x32_bf16(ahi[ks], blo, acc[nt], 0, 0, 0);
            }
        }
    } else {
#pragma unroll
        for (int ks = 0; ks < 4; ++ks) {
#pragma unroll
            for (int nt = 0; nt < 8; ++nt) {
                int row = nt * 16 + lr;
                int bo = (row * 256 + ks * 64 + lk * 16) ^ ((lr & 7) << 4);
                short8v bhi = *(const short8v*)((const char*)Wh + bo);
                short8v blo = *(const short8v*)(Wlo + row * HID + ks * 32 + lk * 8);
                acc[nt] = __builtin_amdgcn_mfma_f32_16x16x32_bf16(ahi[ks], bhi, acc[nt], 0, 0, 0);
                acc[nt] = __builtin_amdgcn_mfma_f32_16x16x32_bf16(alo[ks], bhi, acc[nt], 0, 0, 0);
                acc[nt] = __builtin_amdgcn_mfma_f32_16x16x32_bf16(ahi[ks], blo, acc[nt], 0, 0, 0);
            }
        }
    }

    // ---- epilogue: alpha logits from fp32 acc, then bf16 x store (row-major) ----
    float ps[4] = {0.f, 0.f, 0.f, 0.f};
    float pd[4] = {0.f, 0.f, 0.f, 0.f};
#pragma unroll
    for (int nt = 0; nt < 8; ++nt) {
        float asv = a_s[nt * 16 + lr];
        float adv = a_d[nt * 16 + lr];
#pragma unroll
        for (int r = 0; r < 4; ++r) {
            ps[r] = fmaf(acc[nt][r], asv, ps[r]);
            pd[r] = fmaf(acc[nt][r], adv, pd[r]);
        }
    }
#pragma unroll
    for (int m = 8; m >= 1; m >>= 1) {
#pragma unroll
        for (int r = 0; r < 4; ++r) {
            ps[r] += __shfl_xor(ps[r], m, 16);   // reduce across the 16 col-lanes
            pd[r] += __shfl_xor(pd[r], m, 16);
        }
    }
#pragma unroll
    for (int r = 0; r < 4; ++r) {
        int grow = base + w * 16 + lk * 4 + r;
        if (grow < NN) {
#pragma unroll
            for (int nt = 0; nt < 8; ++nt)
                x[(size_t)grow * HID + nt * 16 + lr] = f2b(acc[nt][r]);
            if (lr == 0) { alpha_s[grow] = ps[r]; alpha_d[grow] = pd[r]; }
        }
    }
}

// ---------- fused softmax + aggregation v4: readlane distribution ----------
// Phase 1 unchanged (one exp per edge, butterfly denominator, normalized p).
// Phase 2: (idx_j, p_j) distributed via v_readlane (SALU/SGPR) instead of
// __shfl (ds_bpermute): kills 128 LDS-pipe ops per wave AND turns each gather
// into global_load with SGPR row base + lane offset (no 64-bit VALU address
// math). Group-level wave-uniform break trims padded chunks; intra-group
// padding lanes read row 0 with p = 0 (contributes nothing, L1-hot).
// [R5 counters: VALUBusy 50% @ HBM 35% -> issue/VALU was the gather limiter]
__global__ __launch_bounds__(256) void aggregate_v4(
        const unsigned short* __restrict__ x, const int* __restrict__ deg_,
        const int* __restrict__ csr, const float* __restrict__ als,
        const float* __restrict__ ald, const float* __restrict__ bias,
        void* __restrict__ out, const int* __restrict__ flag, int do_relu) {
    const int node = (blockIdx.x * 256 + threadIdx.x) >> 6;
    const int lane = threadIdx.x & 63;
    if (node >= NN) return;
    const int deg = min(deg_[node], CAP);

    // ---- phase 1: softmax weights, one lane per slot ----
    int   sidx = 0;
    float p    = 0.f;
    if (lane < deg) {
        sidx = csr[(node << 6) + lane];              // coalesced 256-B read
        float e = als[sidx] + ald[node];             // gather + broadcast
        e = fmaxf(e, NEG_SLOPE * e);                 // leaky_relu
        e = fminf(e, 60.f);                          // inf hardening
        p = __expf(e);
    }
    float den = p;
#pragma unroll
    for (int m = 1; m < 64; m <<= 1) den += __shfl_xor(den, m);
    p *= 1.f / (den + 1e-16f);                       // normalized; 0 on padding lanes

    // ---- phase 2: gather + weighted accumulate, lane = 2 cols ----
    const unsigned int* x2 = (const unsigned int*)x; // ushort2 as u32
    float ax = 0.f, ay = 0.f;
#pragma unroll
    for (int j0 = 0; j0 < CAP; j0 += 16) {
        if (j0 >= deg) break;                        // wave-uniform group skip
        unsigned int u[16]; float pj[16];
#pragma unroll
        for (int k = 0; k < 16; ++k) {
            const int j = j0 + k;                    // compile-time lane index
            int ijs = __builtin_amdgcn_readlane(sidx, j);    // SGPR broadcast
            pj[k] = readlane_f(p, j);                        // SGPR broadcast
            const unsigned int* rowp = x2 + (((size_t)(unsigned)ijs) << 6);
            u[k] = rowp[lane];                       // SGPR base + lane offset
        }
#pragma unroll
        for (int k = 0; k < 16; ++k) {
            ax = fmaf(pj[k], f_lo(u[k]), ax);
            ay = fmaf(pj[k], f_hi(u[k]), ay);
        }
    }

    float2 bv = ((const float2*)bias)[lane];
    float ox = ax + bv.x;
    float oy = ay + bv.y;
    if (do_relu) { ox = fmaxf(ox, 0.f); oy = fmaxf(oy, 0.f); }
    if (*flag) {
        ushort2 pk; pk.x = f2b(ox); pk.y = f2b(oy);
        *(ushort2*)((unsigned short*)out + (size_t)node * HID + lane * 2) = pk;
    } else {
        ((float2*)out)[(size_t)node * 64 + lane] = make_float2(ox, oy);
    }
}

extern "C" void kernel_launch(void* const* d_in, const int* in_sizes, int n_in,
                              void* d_out, int out_size, void* d_ws, size_t ws_size,
                              hipStream_t stream) {
    const void* z_in  = d_in[0];
    const int*  ei    = (const int*)d_in[1];
    const void* Ws_in = d_in[2];
    const void* as_in = d_in[3];
    const void* ad_in = d_in[4];
    const void* b_in  = d_in[5];

    char* wsp = (char*)d_ws;
    auto alloc = [&](size_t bytes) -> char* {
        char* p = wsp; wsp += (bytes + 255) & ~(size_t)255; return p;
    };
    int*            dflag   = (int*)alloc(4);
    int*            pos     = (int*)alloc(NN * 4);               // degree array
    int*            csrp    = (int*)alloc((size_t)NN * CAP * 4); // padded CSR (12.8 MB)
    float*          alpha_s = (float*)alloc(NN * 4);
    float*          alpha_d = (float*)alloc(NN * 4);
    unsigned short* Wb      = (unsigned short*)alloc((size_t)3 * 2 * HID * HID * 2); // hi(swz)+lo W
    float*          asf     = (float*)alloc(3 * HID * 4);
    float*          adf     = (float*)alloc(3 * HID * 4);
    float*          bff     = (float*)alloc(3 * HID * 4);
    unsigned short* xb      = (unsigned short*)alloc((size_t)NN * HID * 2);  // row-major bf16 x

    // fused prep: flag + W split/swizzle + vectors + pos zero
    prep<<<197, 256, 0, stream>>>((const unsigned short*)z_in, Ws_in, as_in, ad_in, b_in,
                                  Wb, asf, adf, bff, pos, dflag);

    // padded CSR build: single swizzled scatter pass
    const int chunks = (ET + SCHUNK - 1) / SCHUNK;
    scatter_padded<<<chunks * 8, 256, 0, stream>>>(ei, pos, csrp);

    const int gemm_blocks = (NN + 63) / 64;
    const int wave_blocks = (NN + 3) / 4;   // 4 waves (nodes) per 256-thread block
    const size_t WL = 2 * HID * HID;        // per-layer Wb stride (ushorts)

    // layer 0
    gemm_alpha<<<gemm_blocks, 256, 0, stream>>>(z_in, Wb, asf, adf, xb, alpha_s, alpha_d, dflag);
    aggregate_v4<<<wave_blocks, 256, 0, stream>>>(xb, pos, csrp, alpha_s, alpha_d, bff, d_out, dflag, 1);

    // layer 1 (d_out ping-pong: aggregate reads only xb/als/csr — overwrite safe)
    gemm_alpha<<<gemm_blocks, 256, 0, stream>>>(d_out, Wb + WL, asf + HID, adf + HID,
                                                xb, alpha_s, alpha_d, dflag);
    aggregate_v4<<<wave_blocks, 256, 0, stream>>>(xb, pos, csrp, alpha_s, alpha_d, bff + HID, d_out, dflag, 1);

    // layer 2 (final, no relu)
    gemm_alpha<<<gemm_blocks, 256, 0, stream>>>(d_out, Wb + 2 * WL, asf + 2 * HID,
                                                adf + 2 * HID, xb, alpha_s, alpha_d, dflag);
    aggregate_v4<<<wave_blocks, 256, 0, stream>>>(xb, pos, csrp, alpha_s, alpha_d, bff + 2 * HID, d_out, dflag, 0);
}